// Round 1
// baseline (45.859 us; speedup 1.0000x reference)
//
#include <hip/hip_runtime.h>

// Problem constants (fixed by reference setup_inputs)
#define M_PTS 4096      // T*N
#define DIM 64          // D
#define NLAT 4          // Z
#define TILE 128
#define TPB 256
#define NTILE (M_PTS / TILE)   // 32
#define JITTER_F 0.002f
#define NEG_HALF_LOG2E (-0.72134752044448170f)  // -0.5 * log2(e)

__device__ __forceinline__ float fast_exp2(float x) {
#if defined(__has_builtin)
#if __has_builtin(__builtin_amdgcn_exp2f)
  return __builtin_amdgcn_exp2f(x);
#else
  return exp2f(x);
#endif
#else
  return exp2f(x);
#endif
}

// One block computes a 128x128 tile of cov for tile-pair (bi, bj), bj >= bi,
// and writes both the tile and its transpose (cov is exactly symmetric).
// K = 64 fits in a single LDS stage; no K loop over tiles.
__global__ __launch_bounds__(TPB) void cov_kernel(
    const float* __restrict__ X,      // [M_PTS, DIM]
    const float* __restrict__ W,      // [T=4, Z=4]
    const float* __restrict__ theta,  // [Z=4, 2]
    float* __restrict__ out) {        // [M_PTS, M_PTS]
  // Swizzled tiles: element (row,k) at [row*64 + ((k>>2 ^ row>>3)<<2) + (k&3)]
  __shared__ float As[TILE * DIM];   // 32 KB
  __shared__ float Bs[TILE * DIM];   // 32 KB  (total 64 KB -> 2 blocks/CU)

  // ---- triangular tile decode (uniform scalar) ----
  int rem = blockIdx.x;
  int bi = 0;
  while (rem >= NTILE - bi) { rem -= NTILE - bi; ++bi; }
  const int bj = bi + rem;

  const int tid = threadIdx.x;
  const int tx = tid & 15;          // 0..15 -> output cols j0 = tx*8
  const int ty = tid >> 4;          // 0..15 -> output rows i0 = ty*8
  const int gi0 = bi * TILE;
  const int gj0 = bj * TILE;

  // ---- stage A,B tiles (swizzled) + row-norm partial reduction ----
  // staging mapping: kg0 = float4-group (0..15), r4 selects row within pass
  const int kg0 = tid & 15;
  const int r4 = tid >> 4;          // 0..15
  float mysum = 0.0f;               // one row-sum kept per thread
#pragma unroll
  for (int p = 0; p < 8; ++p) {
    const int row = p * 16 + r4;    // 0..127
    const int sw = ((kg0 ^ (row >> 3)) << 2);
    float4 a = *(const float4*)&X[(size_t)(gi0 + row) * DIM + kg0 * 4];
    float4 b = *(const float4*)&X[(size_t)(gj0 + row) * DIM + kg0 * 4];
    *(float4*)&As[row * DIM + sw] = a;
    *(float4*)&Bs[row * DIM + sw] = b;
    float sa = a.x * a.x + a.y * a.y + a.z * a.z + a.w * a.w;
    float sb = b.x * b.x + b.y * b.y + b.z * b.z + b.w * b.w;
    // 16-lane group reduce (lanes sharing a row are contiguous 16 lanes)
#pragma unroll
    for (int m = 1; m < 16; m <<= 1) {
      sa += __shfl_xor(sa, m);
      sb += __shfl_xor(sb, m);
    }
    if (kg0 == p) mysum = sa;           // keep A row (p*16 + r4)
    if (kg0 == p + 8) mysum = sb;       // keep B row (p*16 + r4)
  }
  __syncthreads();

  // ---- main product: acc[r][c] = dot(X[gi0+i0+r], X[gj0+j0+c]) ----
  const int i0 = ty * 8;
  const int j0 = tx * 8;
  float acc[8][8] = {};
#pragma unroll 2
  for (int kg = 0; kg < 16; ++kg) {
    float4 a4[8], b4[8];
    const int swa = ((kg ^ ty) << 2);
    const int swb = ((kg ^ tx) << 2);
#pragma unroll
    for (int r = 0; r < 8; ++r) a4[r] = *(const float4*)&As[(i0 + r) * DIM + swa];
#pragma unroll
    for (int c = 0; c < 8; ++c) b4[c] = *(const float4*)&Bs[(j0 + c) * DIM + swb];
#pragma unroll
    for (int r = 0; r < 8; ++r)
#pragma unroll
      for (int c = 0; c < 8; ++c) {
        acc[r][c] = fmaf(a4[r].x, b4[c].x, acc[r][c]);
        acc[r][c] = fmaf(a4[r].y, b4[c].y, acc[r][c]);
        acc[r][c] = fmaf(a4[r].z, b4[c].z, acc[r][c]);
        acc[r][c] = fmaf(a4[r].w, b4[c].w, acc[r][c]);
      }
  }

  // ---- publish row norms into (now-dead) As[0..255] ----
  __syncthreads();
  {
    const int idx = (kg0 < 8) ? (kg0 * 16 + r4) : (128 + (kg0 - 8) * 16 + r4);
    As[idx] = mysum;
  }
  __syncthreads();

  // ---- epilogue: RBF mix over Z latents ----
  const int ti = bi >> 3;   // 1024 rows per task / 128 per tile = 8 tiles/task
  const int tj = bj >> 3;
  float cz[NLAT], ez[NLAT];
#pragma unroll
  for (int z = 0; z < NLAT; ++z) {
    cz[z] = W[ti * NLAT + z] * W[tj * NLAT + z] * theta[2 * z];
    ez[z] = NEG_HALF_LOG2E * theta[2 * z + 1];
  }
  float sqa[8], sqb[8];
#pragma unroll
  for (int r = 0; r < 8; ++r) sqa[r] = As[i0 + r];
#pragma unroll
  for (int c = 0; c < 8; ++c) sqb[c] = As[128 + j0 + c];

#pragma unroll
  for (int r = 0; r < 8; ++r)
#pragma unroll
    for (int c = 0; c < 8; ++c) {
      float sd = fmaxf(fmaf(-2.0f, acc[r][c], sqa[r] + sqb[c]), 0.0f);
      float v = 0.0f;
#pragma unroll
      for (int z = 0; z < NLAT; ++z) v = fmaf(cz[z], fast_exp2(ez[z] * sd), v);
      acc[r][c] = v;
    }
  if (bi == bj && ty == tx) {
#pragma unroll
    for (int r = 0; r < 8; ++r) acc[r][r] += JITTER_F;
  }

  // ---- stores: tile and (off-diagonal) its transpose ----
#pragma unroll
  for (int r = 0; r < 8; ++r) {
    const size_t base = (size_t)(gi0 + i0 + r) * M_PTS + (gj0 + j0);
    *(float4*)&out[base] = make_float4(acc[r][0], acc[r][1], acc[r][2], acc[r][3]);
    *(float4*)&out[base + 4] = make_float4(acc[r][4], acc[r][5], acc[r][6], acc[r][7]);
  }
  if (bi != bj) {
#pragma unroll
    for (int c = 0; c < 8; ++c) {
      const size_t base = (size_t)(gj0 + j0 + c) * M_PTS + (gi0 + i0);
      *(float4*)&out[base] = make_float4(acc[0][c], acc[1][c], acc[2][c], acc[3][c]);
      *(float4*)&out[base + 4] = make_float4(acc[4][c], acc[5][c], acc[6][c], acc[7][c]);
    }
  }
}

extern "C" void kernel_launch(void* const* d_in, const int* in_sizes, int n_in,
                              void* d_out, int out_size, void* d_ws, size_t ws_size,
                              hipStream_t stream) {
  const float* x = (const float*)d_in[0];      // (4,1024,64) fp32
  const float* W = (const float*)d_in[1];      // (4,4) fp32
  const float* theta = (const float*)d_in[2];  // (4,2) fp32
  float* out = (float*)d_out;                  // (4096,4096) fp32

  const int ntri = NTILE * (NTILE + 1) / 2;    // 528 blocks
  cov_kernel<<<dim3(ntri), dim3(TPB), 0, stream>>>(x, W, theta, out);
}